// Round 7
// baseline (654.575 us; speedup 1.0000x reference)
//
#include <hip/hip_runtime.h>

#define N_USERS 100000
#define N_ITEMS 50000
#define N_NODES 150000
#define N_REL 5
#define NNZ 2000000
#define D 64
#define B_EVAL 16384
#define MAXSLOTS 32768
#define NBINS (MAXSLOTS * N_REL)      /* 163840 */
#define TOTAL_EDGES (N_REL * NNZ)     /* 10,000,000 */

// -------- workspace layout (bytes) ----
// map:    int[150000]          @ 0
// cnt:    int                  @ 600,064
// bincnt: int[163840]          @ 600,128
// agg:    u64[163840*32]       @ 1,255,488   (41.9 MB)  2 dims packed per u64
// logits: float[32768*64]      @ 43,198,528  ( 8.4 MB)  -> total 51.6 MB
#define OFF_MAP   0
#define OFF_CNT   600064
#define OFF_BCNT  600128
#define OFF_AGG   1255488
#define OFF_LOG   43198528

// fixed-point: q = rn((c + 1.0) * 2^23), c = v*E in [-0.7, 0.7]
// per-u64-half sum <= 60 * 1.7 * 2^23 = 8.6e8 < 2^32  -> no cross-field carry
#define FP_SCALE 8388608.0f
#define FP_INV   1.1920929e-7f

__device__ __forceinline__ unsigned short f2bf(float f) {   // RNE f32->bf16
    unsigned u = __float_as_uint(f);
    return (unsigned short)((u + 0x7FFFu + ((u >> 16) & 1u)) >> 16);
}
__device__ __forceinline__ float bflo(unsigned p) { return __uint_as_float(p << 16); }
__device__ __forceinline__ float bfhi(unsigned p) { return __uint_as_float(p & 0xFFFF0000u); }

__global__ __launch_bounds__(256) void build_map(const int* __restrict__ users,
                                                 const int* __restrict__ items,
                                                 int* __restrict__ map,
                                                 int* __restrict__ cnt) {
    int t = blockIdx.x * 256 + threadIdx.x;
    if (t >= 2 * B_EVAL) return;
    int node = (t < B_EVAL) ? users[t] : (N_USERS + items[t - B_EVAL]);
    if (atomicCAS(&map[node], -1, -2) == -1) {
        int idx = atomicAdd(cnt, 1);
        map[node] = idx;
    }
}

// one pass over all edges; passing edges do 32 packed-u64 atomics (2 dims each)
__global__ __launch_bounds__(256) void scatter_edges(const int* __restrict__ rows,
                                                     const int* __restrict__ cols,
                                                     const float* __restrict__ vals,
                                                     const float* __restrict__ uemb,
                                                     const float* __restrict__ iemb,
                                                     const int* __restrict__ map,
                                                     unsigned long long* __restrict__ agg,
                                                     int* __restrict__ bincnt) {
    int gid = blockIdx.x * 256 + threadIdx.x;
    int lane = threadIdx.x & 63;
    int half = lane >> 5;        // which of 2 edges this lane serves
    int sub  = lane & 31;        // u64 index within the 32-u64 row

    int pass = 0, ci = -1, c = 0, k = 0;
    float v = 0.0f;
    if (gid < TOTAL_EDGES) {
        int r = rows[gid];
        ci = map[r];
        if (ci >= 0) {
            pass = 1;
            c = cols[gid];
            v = vals[gid];
            k = gid / NNZ;
        }
    }
    unsigned long long m = __ballot(pass);
    while (m) {
        int src0 = __ffsll(m) - 1; m &= m - 1;
        int src1 = src0;
        bool have2 = (m != 0);
        if (have2) { src1 = __ffsll(m) - 1; m &= m - 1; }
        int src = half ? src1 : src0;
        bool act = (half == 0) || have2;
        int   cci = __shfl(ci, src);
        int   cc  = __shfl(c, src);
        int   ck  = __shfl(k, src);
        float cv  = __shfl(v, src);
        if (act) {
            int bin = cci * N_REL + ck;
            const float2* er = (const float2*)((cc < N_USERS) ? uemb + (size_t)cc * D
                                                              : iemb + (size_t)(cc - N_USERS) * D);
            float2 e = er[sub];
            unsigned q0 = (unsigned)__float2int_rn(fmaf(cv, e.x, 1.0f) * FP_SCALE);
            unsigned q1 = (unsigned)__float2int_rn(fmaf(cv, e.y, 1.0f) * FP_SCALE);
            unsigned long long pk = ((unsigned long long)q1 << 32) | (unsigned long long)q0;
            atomicAdd(&agg[(size_t)bin * 32 + sub], pk);
            if (sub == 0) atomicAdd(&bincnt[bin], 1);
        }
    }
}

// LDS-tiled fused dense: 32 slots/block, 256 threads, 2x4 register tile/thread.
// Dequantizes fixed-point agg during LDS staging.
// LDS: shA bf16[32][328] + shM1 bf16[32][328] + shW f32[64][68] = 59,392 B.
__global__ __launch_bounds__(256) void dense_tile(const unsigned long long* __restrict__ agg,
                                                  const int* __restrict__ bincnt,
                                                  const float* __restrict__ Wrel,
                                                  const float* __restrict__ brel,
                                                  const float* __restrict__ affW,
                                                  const float* __restrict__ affb,
                                                  const int* __restrict__ cnt,
                                                  float* __restrict__ logits) {
    __shared__ __align__(16) unsigned short shA[32][328];
    __shared__ __align__(16) unsigned short shM1[32][328];
    __shared__ __align__(16) float shW[64][68];

    int tid = threadIdx.x;
    int ty = tid >> 4, tx = tid & 15;
    int s0 = ty * 2;                    // 2 slots per thread
    int j0 = tx * 4;                    // 4 cols per thread
    int cval = *cnt;

    for (int tile = blockIdx.x; tile * 32 < cval; tile += gridDim.x) {
        __syncthreads();   // protect shA/shM1 reuse across tiles
        // ---- stage A tile: 32 slots x 160 u64 -> dequant -> bf16 LDS ----
        {
            const uint2* src = (const uint2*)(agg + (size_t)tile * 32 * 160);
            #pragma unroll
            for (int i = 0; i < 20; i++) {
                int idx = tid + i * 256;          // 0..5119
                int slot = idx / 160;
                int rem  = idx - slot * 160;      // rel*32 + du
                int rel = rem >> 5, du = rem & 31;
                uint2 q = src[idx];
                float n = (float)bincnt[(tile * 32 + slot) * N_REL + rel];
                float a0 = fmaf((float)q.x, FP_INV, -n);
                float a1 = fmaf((float)q.y, FP_INV, -n);
                unsigned pk = (unsigned)f2bf(a0) | ((unsigned)f2bf(a1) << 16);
                *(unsigned*)&shA[slot][rel * 64 + 2 * du] = pk;
            }
        }
        // ---- stage 1: per-relation 64x64 transform + leaky ----
        #pragma unroll
        for (int k = 0; k < N_REL; k++) {
            __syncthreads();
            const float4* wsrc = (const float4*)(Wrel + (size_t)k * 4096);
            #pragma unroll
            for (int i = 0; i < 4; i++) {
                int idx = tid + i * 256;
                *(float4*)&shW[idx >> 4][(idx & 15) * 4] = wsrc[idx];
            }
            __syncthreads();
            float acc[2][4];
            #pragma unroll
            for (int jj = 0; jj < 4; jj++) {
                float b = brel[k * 64 + j0 + jj];
                acc[0][jj] = b; acc[1][jj] = b;
            }
            for (int d = 0; d < 64; d += 2) {
                unsigned pa0 = *(const unsigned*)&shA[s0][k * 64 + d];
                unsigned pa1 = *(const unsigned*)&shA[s0 + 1][k * 64 + d];
                float4 w0 = *(const float4*)&shW[d][j0];
                float4 w1 = *(const float4*)&shW[d + 1][j0];
                float a00 = bflo(pa0), a01 = bfhi(pa0);
                float a10 = bflo(pa1), a11 = bfhi(pa1);
                acc[0][0] = fmaf(a00, w0.x, fmaf(a01, w1.x, acc[0][0]));
                acc[0][1] = fmaf(a00, w0.y, fmaf(a01, w1.y, acc[0][1]));
                acc[0][2] = fmaf(a00, w0.z, fmaf(a01, w1.z, acc[0][2]));
                acc[0][3] = fmaf(a00, w0.w, fmaf(a01, w1.w, acc[0][3]));
                acc[1][0] = fmaf(a10, w0.x, fmaf(a11, w1.x, acc[1][0]));
                acc[1][1] = fmaf(a10, w0.y, fmaf(a11, w1.y, acc[1][1]));
                acc[1][2] = fmaf(a10, w0.z, fmaf(a11, w1.z, acc[1][2]));
                acc[1][3] = fmaf(a10, w0.w, fmaf(a11, w1.w, acc[1][3]));
            }
            #pragma unroll
            for (int i = 0; i < 2; i++) {
                #pragma unroll
                for (int jj = 0; jj < 4; jj++) {
                    float vv = acc[i][jj];
                    acc[i][jj] = (vv > 0.0f) ? vv : 0.2f * vv;   // leaky_relu 0.2
                }
                unsigned lo = (unsigned)f2bf(acc[i][0]) | ((unsigned)f2bf(acc[i][1]) << 16);
                unsigned hi = (unsigned)f2bf(acc[i][2]) | ((unsigned)f2bf(acc[i][3]) << 16);
                *(uint2*)&shM1[s0 + i][k * 64 + j0] = make_uint2(lo, hi);
            }
        }
        // ---- stage 2: [32x320] x [320x64] affine ----
        float acc2[2][4] = {{0,0,0,0},{0,0,0,0}};
        #pragma unroll
        for (int c = 0; c < N_REL; c++) {
            __syncthreads();
            const float4* wsrc = (const float4*)(affW + (size_t)c * 4096);
            #pragma unroll
            for (int i = 0; i < 4; i++) {
                int idx = tid + i * 256;
                *(float4*)&shW[idx >> 4][(idx & 15) * 4] = wsrc[idx];
            }
            __syncthreads();
            for (int dd = 0; dd < 64; dd += 2) {
                unsigned m0 = *(const unsigned*)&shM1[s0][c * 64 + dd];
                unsigned m1 = *(const unsigned*)&shM1[s0 + 1][c * 64 + dd];
                float4 w0 = *(const float4*)&shW[dd][j0];
                float4 w1 = *(const float4*)&shW[dd + 1][j0];
                float a00 = bflo(m0), a01 = bfhi(m0);
                float a10 = bflo(m1), a11 = bfhi(m1);
                acc2[0][0] = fmaf(a00, w0.x, fmaf(a01, w1.x, acc2[0][0]));
                acc2[0][1] = fmaf(a00, w0.y, fmaf(a01, w1.y, acc2[0][1]));
                acc2[0][2] = fmaf(a00, w0.z, fmaf(a01, w1.z, acc2[0][2]));
                acc2[0][3] = fmaf(a00, w0.w, fmaf(a01, w1.w, acc2[0][3]));
                acc2[1][0] = fmaf(a10, w0.x, fmaf(a11, w1.x, acc2[1][0]));
                acc2[1][1] = fmaf(a10, w0.y, fmaf(a11, w1.y, acc2[1][1]));
                acc2[1][2] = fmaf(a10, w0.z, fmaf(a11, w1.z, acc2[1][2]));
                acc2[1][3] = fmaf(a10, w0.w, fmaf(a11, w1.w, acc2[1][3]));
            }
        }
        float4 ab = *(const float4*)&affb[j0];
        #pragma unroll
        for (int i = 0; i < 2; i++) {
            float4 r;
            r.x = acc2[i][0] + ab.x; r.y = acc2[i][1] + ab.y;
            r.z = acc2[i][2] + ab.z; r.w = acc2[i][3] + ab.w;
            *(float4*)&logits[(size_t)(tile * 32 + s0 + i) * 64 + j0] = r;
        }
    }
}

__global__ __launch_bounds__(256) void finalize(const int* __restrict__ users,
                                                const int* __restrict__ items,
                                                const int* __restrict__ map,
                                                const float* __restrict__ logits,
                                                float* __restrict__ out) {
    int wave = (blockIdx.x * 256 + threadIdx.x) >> 6;
    int lane = threadIdx.x & 63;
    if (wave >= B_EVAL) return;
    int cu = map[users[wave]];
    int ci = map[N_USERS + items[wave]];
    float p = logits[(size_t)cu * D + lane] * logits[(size_t)ci * D + lane];
    #pragma unroll
    for (int off = 32; off > 0; off >>= 1) p += __shfl_down(p, off);
    if (lane == 0) out[wave] = p;
}

extern "C" void kernel_launch(void* const* d_in, const int* in_sizes, int n_in,
                              void* d_out, int out_size, void* d_ws, size_t ws_size,
                              hipStream_t stream) {
    const int*   users = (const int*)d_in[0];
    const int*   items = (const int*)d_in[1];
    const int*   rows  = (const int*)d_in[2];
    const int*   cols  = (const int*)d_in[3];
    const float* vals  = (const float*)d_in[4];
    const float* uemb  = (const float*)d_in[5];
    const float* iemb  = (const float*)d_in[6];
    const float* Wrel  = (const float*)d_in[7];
    const float* brel  = (const float*)d_in[8];
    const float* affW  = (const float*)d_in[9];
    const float* affb  = (const float*)d_in[10];
    float* out = (float*)d_out;

    char* ws = (char*)d_ws;
    int* map    = (int*)(ws + OFF_MAP);
    int* cnt    = (int*)(ws + OFF_CNT);
    int* bincnt = (int*)(ws + OFF_BCNT);
    unsigned long long* agg = (unsigned long long*)(ws + OFF_AGG);
    float* logits = (float*)(ws + OFF_LOG);

    // workspace re-poisoned before every call: re-init every time
    (void)hipMemsetAsync(map, 0xFF, (size_t)N_NODES * sizeof(int), stream);  // map = -1
    (void)hipMemsetAsync(cnt, 0, sizeof(int), stream);
    (void)hipMemsetAsync(bincnt, 0, (size_t)NBINS * sizeof(int), stream);
    (void)hipMemsetAsync(agg, 0, (size_t)NBINS * 32 * sizeof(unsigned long long), stream);

    build_map<<<(2 * B_EVAL + 255) / 256, 256, 0, stream>>>(users, items, map, cnt);
    scatter_edges<<<(TOTAL_EDGES + 255) / 256, 256, 0, stream>>>(rows, cols, vals, uemb, iemb,
                                                                 map, agg, bincnt);
    dense_tile<<<1024, 256, 0, stream>>>(agg, bincnt, Wrel, brel, affW, affb, cnt, logits);
    finalize<<<(B_EVAL * 64) / 256, 256, 0, stream>>>(users, items, map, logits, out);
}